// Round 19
// baseline (252.562 us; speedup 1.0000x reference)
//
#include <hip/hip_runtime.h>
#include <stdint.h>

#define N_NODES 50000
#define N_EDGES 1600000
#define HID 128
#define NB 196      // dst buckets of 256 nodes
#define CHUNK 8192
#define NCH 196     // ceil(1600000 / 8192)
#define TOT (NB * NCH)
#define NGB 6250    // gather_h0 blocks (N*32/256)
#define NCW 1152    // convert_w blocks
#define NMB 782     // gemm 64-row tiles

typedef float f32x4 __attribute__((ext_vector_type(4)));
typedef float f32x2 __attribute__((ext_vector_type(2)));
typedef short s16x8 __attribute__((ext_vector_type(8)));
typedef unsigned u32x4 __attribute__((ext_vector_type(4)));

// permuted X/h column layout: natural col c lives at position p
//   p(c) = (c&15)*8 + (c>>4)      c(p) = (p&7)*16 + (p>>3)
__device__ __forceinline__ int pos2col(int p) { return (p & 7) * 16 + (p >> 3); }

__device__ __forceinline__ unsigned short f2bf(float f) {
  unsigned u = __float_as_uint(f);
  u += 0x7fffu + ((u >> 16) & 1u);   // RNE
  return (unsigned short)(u >> 16);
}

__device__ __forceinline__ int block_scan_excl(int v, int t) {
  const int lane = t & 63, wid = t >> 6;
  int incl = v;
  #pragma unroll
  for (int o = 1; o < 64; o <<= 1) {
    int nv = __shfl_up(incl, o);
    if (lane >= o) incl += nv;
  }
  __shared__ int wsum[4];
  if (lane == 63) wsum[wid] = incl;
  __syncthreads();
  int wbase = 0;
  #pragma unroll
  for (int w = 0; w < 3; ++w) if (w < wid) wbase += wsum[w];
  return wbase + incl - v;
}

// ---- pre-kernel: gather_h0(perm) | chunk_hist | convert_w(perm-d) | biasP ----
__global__ void k_pre(const int* __restrict__ nid, const float* __restrict__ emb,
                      unsigned short* __restrict__ h0,
                      const int* __restrict__ dst, int* __restrict__ histT,
                      const float* __restrict__ W, const float* __restrict__ Wl,
                      unsigned short* __restrict__ Wt,
                      const float* __restrict__ bias, float* __restrict__ biasP) {
  const int bid = blockIdx.x, t = threadIdx.x;
  if (bid < NGB) {                       // h0[i][p] = bf16(emb[nid[i]][c(p)])
    int g = bid * 256 + t;
    int i = g >> 5, s = g & 31;
    const float* erow = emb + (size_t)nid[i] * HID;
    ushort4 o;
    o.x = f2bf(erow[pos2col(4 * s + 0)]);
    o.y = f2bf(erow[pos2col(4 * s + 1)]);
    o.z = f2bf(erow[pos2col(4 * s + 2)]);
    o.w = f2bf(erow[pos2col(4 * s + 3)]);
    *(ushort4*)(h0 + (size_t)i * HID + 4 * s) = o;
  } else if (bid < NGB + NCH) {          // per-chunk bucket histogram
    __shared__ int h[NB];
    const int c = bid - NGB;
    if (t < NB) h[t] = 0;
    __syncthreads();
    int base = c * CHUNK;
    #pragma unroll 4
    for (int i = t; i < CHUNK; i += 256) {
      int e = base + i;
      if (e < N_EDGES) atomicAdd(&h[dst[e] >> 8], 1);
    }
    __syncthreads();
    if (t < NB) histT[t * NCH + c] = h[t];
  } else if (bid < NGB + NCH + NCW) {    // Wt[l][r][k][p] = W[l][r][c(p)][k]
    int idx = (bid - NGB - NCH) * 256 + t;
    int p  = idx & 127;
    int k  = (idx >> 7) & 127;
    int lr = idx >> 14;
    int l = lr / 9, r = lr - l * 9;
    int d = pos2col(p);
    float v;
    if (r < 8) v = W[((((size_t)l * 8 + r) * 128) + d) * 128 + k];
    else       v = Wl[(((size_t)l * 128) + d) * 128 + k];
    Wt[idx] = f2bf(v);
  } else {                               // biasP[l][p] = bias[l][c(p)]
    int l = t >> 7, p = t & 127;
    biasP[t] = bias[l * 128 + pos2col(p)];
  }
}

// ---- CSR pass B1: per-bucket chunk-prefix scan (196 blocks, 1 wave each) ----
__global__ void k_scan_buckets(const int* __restrict__ histT, int* __restrict__ curL,
                               int* __restrict__ btot) {
  const int b = blockIdx.x, tid = threadIdx.x;   // 64 threads
  int carry = 0;
  #pragma unroll
  for (int k = 0; k < 4; ++k) {
    int c = k * 64 + tid;
    int v = (c < NCH) ? histT[b * NCH + c] : 0;
    int incl = v;
    #pragma unroll
    for (int o = 1; o < 64; o <<= 1) {
      int nv = __shfl_up(incl, o);
      if (tid >= o) incl += nv;
    }
    if (c < NCH) curL[b * NCH + c] = carry + incl - v;
    carry += __shfl(incl, 63);
  }
  if (tid == 0) btot[b] = carry;
}

// ---- CSR pass B2: scan 196 bucket totals -> bbase ----
__global__ void k_scan_top(const int* __restrict__ btot, int* __restrict__ bbase,
                           int* __restrict__ rowptr) {
  const int t = threadIdx.x;
  int v = (t < NB) ? btot[t] : 0;
  int ex = block_scan_excl(v, t);
  if (t < NB) bbase[t] = ex;
  if (t == 0) { bbase[NB] = N_EDGES; rowptr[N_NODES] = N_EDGES; }
}

// ---- GEMM: A in regs, W reg-prefetched (T14 issue-early/write-late),
// ----       single 32KB LDS buffer, syncthreads-only ordering ----
// X[rel][n][p] = sum A[n][.]*Wt[rel][.][.]
template <bool SCAT>
__global__ __launch_bounds__(256, 5) void k_gemm9(
    const unsigned short* __restrict__ A,   // [N][128] bf16 (permuted cols)
    const unsigned short* __restrict__ Bw,  // [9][128][128] bf16 (k x perm-d)
    unsigned short* __restrict__ X,         // [9][N][128] bf16 (permuted cols)
    const int* __restrict__ src, const int* __restrict__ dst,
    const int* __restrict__ et, const int* __restrict__ curL,
    const int* __restrict__ bbase, unsigned* __restrict__ tmp) {
  __shared__ unsigned char Ws[32768];   // 128 rows x 256B (swizzled)
  const int t = threadIdx.x;
  if (SCAT && blockIdx.x >= NMB) {      // chunk-local scatter role
    int* off2 = (int*)Ws;               // overlay LDS
    const int c = blockIdx.x - NMB;
    if (t < NB) off2[t] = curL[t * NCH + c] + bbase[t];
    __syncthreads();
    int base = c * CHUNK;
    #pragma unroll 4
    for (int i = t; i < CHUNK; i += 256) {
      int e = base + i;
      if (e < N_EDGES) {
        int d = dst[e];
        int pos = atomicAdd(&off2[d >> 8], 1);
        tmp[pos] = ((unsigned)(d & 255) << 19) | ((unsigned)et[e] << 16) | (unsigned)src[e];
      }
    }
    return;
  }
  const int mb = blockIdx.x;
  const int wid = t >> 6, lane = t & 63;
  const int lr = lane & 15, kg = (lane >> 4) * 8;
  const int rAg = mb * 64 + wid * 16 + lr;
  const bool rok = rAg < N_NODES;
  const unsigned short* Arow = A + (size_t)(rok ? rAg : 0) * 128;
  // hoist A fragments into registers ONCE (rel-invariant): 16 VGPRs
  s16x8 a[4];
  #pragma unroll
  for (int kk = 0; kk < 4; ++kk) {
    s16x8 v = (s16x8)(short)0;
    if (rok) v = *(const s16x8*)(Arow + kk * 32 + kg);
    a[kk] = v;
  }
  const unsigned char* Wb = (const unsigned char*)Bw;
  u32x4 wreg[8];
  // prologue: stage rel 0 (load -> LDS, swizzled; one-time serial cost)
  #pragma unroll
  for (int c = 0; c < 8; ++c)
    wreg[c] = *(const u32x4*)(Wb + c * 4096 + t * 16);
  #pragma unroll
  for (int c = 0; c < 8; ++c) {
    int off = c * 4096 + t * 16;
    int row = off >> 8, ib = off & 255;
    *(u32x4*)(Ws + row * 256 + (ib ^ ((row & 7) << 4))) = wreg[c];
  }
  __syncthreads();

  for (int rel = 0; rel < 9; ++rel) {
    // T14 issue-early: prefetch next rel's W (32KB per rel!) into regs
    if (rel < 8) {
      const unsigned char* gb = Wb + (size_t)(rel + 1) * 32768;
      #pragma unroll
      for (int c = 0; c < 8; ++c)
        wreg[c] = *(const u32x4*)(gb + c * 4096 + t * 16);
    }
    f32x4 acc[8];
    #pragma unroll
    for (int n = 0; n < 8; ++n) acc[n] = (f32x4)(0.f);
    #pragma unroll
    for (int kk = 0; kk < 4; ++kk) {
      const int kb = (kk * 32 + kg) * 2;
      #pragma unroll
      for (int n = 0; n < 8; ++n) {
        int cc = n * 16 + lr;
        s16x8 b = *(const s16x8*)(Ws + cc * 256 + (kb ^ ((cc & 7) << 4)));
        acc[n] = __builtin_amdgcn_mfma_f32_16x16x32_bf16(a[kk], b, acc[n], 0, 0, 0);
      }
    }
    // epilogue: lane's 8 outputs pack into one 16B chunk at permuted positions
    // lr*8..lr*8+7 -> full-line coalesced stores (4 x 256B rows per wave-instr)
    #pragma unroll
    for (int j = 0; j < 4; ++j) {
      int grow = mb * 64 + wid * 16 + (lane >> 4) * 4 + j;
      if (grow < N_NODES) {
        u32x4 pk;
        pk.x = (unsigned)f2bf(acc[0][j]) | ((unsigned)f2bf(acc[1][j]) << 16);
        pk.y = (unsigned)f2bf(acc[2][j]) | ((unsigned)f2bf(acc[3][j]) << 16);
        pk.z = (unsigned)f2bf(acc[4][j]) | ((unsigned)f2bf(acc[5][j]) << 16);
        pk.w = (unsigned)f2bf(acc[6][j]) | ((unsigned)f2bf(acc[7][j]) << 16);
        *(u32x4*)((unsigned char*)X + ((size_t)rel * N_NODES + grow) * 256 + lr * 16) = pk;
      }
    }
    __syncthreads();   // all waves done reading Ws (drains prefetch loads too)
    if (rel < 8) {     // write-late: prefetched W -> LDS, swizzled
      #pragma unroll
      for (int c = 0; c < 8; ++c) {
        int off = c * 4096 + t * 16;
        int row = off >> 8, ib = off & 255;
        *(u32x4*)(Ws + row * 256 + (ib ^ ((row & 7) << 4))) = wreg[c];
      }
      __syncthreads();
    }
  }
}

// ---- CSR finalize: per-node counting sort -> rowptr + u32 keys (et*N+src) ----
__global__ void k_bucket_finalize(const unsigned* __restrict__ tmp,
                                  const int* __restrict__ bbase,
                                  int* __restrict__ rowptr,
                                  unsigned* __restrict__ keys) {
  __shared__ int cnt[256];
  __shared__ int off[256];
  const int b = blockIdx.x;
  const int t = threadIdx.x;
  const int s = bbase[b], e = bbase[b + 1];
  cnt[t] = 0;
  __syncthreads();
  for (int i = s + t; i < e; i += 256)
    atomicAdd(&cnt[(tmp[i] >> 19) & 255u], 1);
  __syncthreads();
  int ex = block_scan_excl(cnt[t], t);
  int node = b * 256 + t;
  if (node < N_NODES) rowptr[node] = s + ex;
  off[t] = s + ex;
  __syncthreads();
  for (int i = s + t; i < e; i += 256) {
    unsigned r = tmp[i];
    int pos = atomicAdd(&off[(r >> 19) & 255u], 1);
    keys[pos] = ((r >> 16) & 7u) * N_NODES + (r & 0xffffu);
  }
}

// ---- per-node aggregation over CSR (permuted cols), 16-deep unroll ----
template <bool LAST>
__global__ void k_aggregate(const unsigned short* __restrict__ X,
                            const unsigned* __restrict__ keys,
                            const int* __restrict__ rowptr,
                            const float* __restrict__ biasP,
                            void* __restrict__ out) {
  __shared__ float ob[4][128];
  const int t = threadIdx.x;
  const int w = t >> 6;
  const int v = blockIdx.x * 4 + w;
  const int lane = t & 63;
  const int start = rowptr[v], end = rowptr[v + 1];
  const unsigned char* Xb = (const unsigned char*)X;
  float a0 = 0.f, a1 = 0.f;
  int e = start;
  const int n16 = start + ((end - start) & ~15);
  for (; e < n16; e += 16) {
    unsigned kk[16], pp[16];
    #pragma unroll
    for (int q = 0; q < 16; ++q) kk[q] = keys[e + q];
    #pragma unroll
    for (int q = 0; q < 16; ++q)
      pp[q] = *(const unsigned*)(Xb + ((size_t)kk[q] << 8) + lane * 4);
    #pragma unroll
    for (int q = 0; q < 16; ++q) {
      a0 += __uint_as_float(pp[q] << 16);
      a1 += __uint_as_float(pp[q] & 0xffff0000u);
    }
  }
  const int n4 = start + ((end - start) & ~3);
  for (; e < n4; e += 4) {
    unsigned kk[4], pp[4];
    #pragma unroll
    for (int q = 0; q < 4; ++q) kk[q] = keys[e + q];
    #pragma unroll
    for (int q = 0; q < 4; ++q)
      pp[q] = *(const unsigned*)(Xb + ((size_t)kk[q] << 8) + lane * 4);
    #pragma unroll
    for (int q = 0; q < 4; ++q) {
      a0 += __uint_as_float(pp[q] << 16);
      a1 += __uint_as_float(pp[q] & 0xffff0000u);
    }
  }
  for (; e < end; ++e) {
    unsigned k0 = keys[e];
    unsigned p0 = *(const unsigned*)(Xb + ((size_t)k0 << 8) + lane * 4);
    a0 += __uint_as_float(p0 << 16); a1 += __uint_as_float(p0 & 0xffff0000u);
  }
  { // self-loop pseudo-relation row
    unsigned p = *(const unsigned*)(Xb + (((size_t)8 * N_NODES + v) << 8) + lane * 4);
    a0 += __uint_as_float(p << 16); a1 += __uint_as_float(p & 0xffff0000u);
  }
  const float2 bb = *(const float2*)(biasP + lane * 2);
  a0 += bb.x; a1 += bb.y;
  if (LAST) {
    // un-permute: position 2L -> natural col c0, 2L+1 -> c0+16
    int c0 = ((2 * lane) & 7) * 16 + (lane >> 2);
    ob[w][c0] = a0;
    ob[w][c0 + 16] = a1;
    __syncthreads();
    f32x2 o = *(const f32x2*)&ob[w][lane * 2];
    __builtin_nontemporal_store(o, (f32x2*)((float*)out + (size_t)v * 128 + lane * 2));
  } else {
    unsigned po = ((unsigned)f2bf(a1) << 16) | (unsigned)f2bf(a0);
    *(unsigned*)((unsigned short*)out + (size_t)v * 128 + lane * 2) = po;
  }
}

extern "C" void kernel_launch(void* const* d_in, const int* in_sizes, int n_in,
                              void* d_out, int out_size, void* d_ws, size_t ws_size,
                              hipStream_t stream) {
  const int*   nid  = (const int*)d_in[0];
  const int*   src  = (const int*)d_in[1];
  const int*   dst  = (const int*)d_in[2];
  const int*   et   = (const int*)d_in[3];
  const float* emb  = (const float*)d_in[4];
  const float* W    = (const float*)d_in[5];
  const float* Wl   = (const float*)d_in[6];
  const float* bias = (const float*)d_in[7];

  unsigned char* ws = (unsigned char*)d_ws;
  size_t off = 0;
  auto alloc = [&](size_t bytes) {
    void* p = ws + off;
    off = (off + bytes + 255) & ~(size_t)255;
    return p;
  };
  unsigned short* X    = (unsigned short*)alloc((size_t)9 * N_NODES * HID * 2);  // 115.2 MB
  unsigned short* h0   = (unsigned short*)alloc((size_t)N_NODES * HID * 2);      // 12.8 MB
  unsigned short* h1   = (unsigned short*)alloc((size_t)N_NODES * HID * 2);      // 12.8 MB
  unsigned short* Wt   = (unsigned short*)alloc((size_t)2 * 9 * 128 * 128 * 2);  // 0.6 MB
  unsigned*       keys = (unsigned*)alloc((size_t)N_EDGES * 4);                  // 6.4 MB
  int*            rowp = (int*)alloc((size_t)(N_NODES + 1) * 4);
  int*            histT= (int*)alloc((size_t)TOT * 4);                           // 150 KB
  int*            curL = (int*)alloc((size_t)TOT * 4);                           // 150 KB
  int*            btot = (int*)alloc((size_t)NB * 4);
  int*            bbas = (int*)alloc((size_t)(NB + 1) * 4);
  float*          biasP= (float*)alloc((size_t)2 * 128 * 4);
  // scatter tmp aliases h1 (dead until aggregate-L0)
  unsigned*       tmp  = (unsigned*)h1;

  k_pre<<<NGB + NCH + NCW + 1, 256, 0, stream>>>(nid, emb, h0, dst, histT, W, Wl, Wt,
                                                 bias, biasP);
  k_scan_buckets<<<NB, 64, 0, stream>>>(histT, curL, btot);
  k_scan_top<<<1, 256, 0, stream>>>(btot, bbas, rowp);
  // gemm layer 0 (782 blocks) + chunk_scatter (196 blocks) fused
  k_gemm9<true><<<NMB + NCH, 256, 0, stream>>>(h0, Wt, X, src, dst, et, curL, bbas, tmp);
  k_bucket_finalize<<<NB, 256, 0, stream>>>(tmp, bbas, rowp, keys);

  const int agrid = N_NODES / 4;                 // 12500, one wave per node
  k_aggregate<false><<<agrid, 256, 0, stream>>>(X, keys, rowp, biasP, (void*)h1);
  k_gemm9<false><<<NMB, 256, 0, stream>>>(h1, Wt + (size_t)9 * 128 * 128, X,
                                          src, dst, et, curL, bbas, tmp);
  k_aggregate<true><<<agrid, 256, 0, stream>>>(X, keys, rowp, biasP + HID, (void*)d_out);
}

// Round 20
// 250.133 us; speedup vs baseline: 1.0097x; 1.0097x over previous
//
#include <hip/hip_runtime.h>
#include <stdint.h>

#define N_NODES 50000
#define N_EDGES 1600000
#define HID 128
#define NB 196      // dst buckets of 256 nodes
#define CHUNK 8192
#define NCH 196     // ceil(1600000 / 8192)
#define TOT (NB * NCH)
#define NGB 6250    // gather_h0 blocks (N*32/256)
#define NCW 1152    // convert_w blocks
#define NMB 782     // gemm 64-row tiles

typedef float f32x4 __attribute__((ext_vector_type(4)));
typedef float f32x2 __attribute__((ext_vector_type(2)));
typedef short s16x8 __attribute__((ext_vector_type(8)));
typedef unsigned u32x4 __attribute__((ext_vector_type(4)));

// permuted X/h column layout: natural col c lives at position p
//   p(c) = (c&15)*8 + (c>>4)      c(p) = (p&7)*16 + (p>>3)
__device__ __forceinline__ int pos2col(int p) { return (p & 7) * 16 + (p >> 3); }

__device__ __forceinline__ unsigned short f2bf(float f) {
  unsigned u = __float_as_uint(f);
  u += 0x7fffu + ((u >> 16) & 1u);   // RNE
  return (unsigned short)(u >> 16);
}

__device__ __forceinline__ int block_scan_excl(int v, int t) {
  const int lane = t & 63, wid = t >> 6;
  int incl = v;
  #pragma unroll
  for (int o = 1; o < 64; o <<= 1) {
    int nv = __shfl_up(incl, o);
    if (lane >= o) incl += nv;
  }
  __shared__ int wsum[4];
  if (lane == 63) wsum[wid] = incl;
  __syncthreads();
  int wbase = 0;
  #pragma unroll
  for (int w = 0; w < 3; ++w) if (w < wid) wbase += wsum[w];
  return wbase + incl - v;
}

// ---- pre-kernel: gather_h0(perm) | chunk_hist | convert_w(perm-d) | biasP ----
__global__ void k_pre(const int* __restrict__ nid, const float* __restrict__ emb,
                      unsigned short* __restrict__ h0,
                      const int* __restrict__ dst, int* __restrict__ histT,
                      const float* __restrict__ W, const float* __restrict__ Wl,
                      unsigned short* __restrict__ Wt,
                      const float* __restrict__ bias, float* __restrict__ biasP) {
  const int bid = blockIdx.x, t = threadIdx.x;
  if (bid < NGB) {                       // h0[i][p] = bf16(emb[nid[i]][c(p)])
    int g = bid * 256 + t;
    int i = g >> 5, s = g & 31;
    const float* erow = emb + (size_t)nid[i] * HID;
    ushort4 o;
    o.x = f2bf(erow[pos2col(4 * s + 0)]);
    o.y = f2bf(erow[pos2col(4 * s + 1)]);
    o.z = f2bf(erow[pos2col(4 * s + 2)]);
    o.w = f2bf(erow[pos2col(4 * s + 3)]);
    *(ushort4*)(h0 + (size_t)i * HID + 4 * s) = o;
  } else if (bid < NGB + NCH) {          // per-chunk bucket histogram
    __shared__ int h[NB];
    const int c = bid - NGB;
    if (t < NB) h[t] = 0;
    __syncthreads();
    int base = c * CHUNK;
    #pragma unroll 4
    for (int i = t; i < CHUNK; i += 256) {
      int e = base + i;
      if (e < N_EDGES) atomicAdd(&h[dst[e] >> 8], 1);
    }
    __syncthreads();
    if (t < NB) histT[t * NCH + c] = h[t];
  } else if (bid < NGB + NCH + NCW) {    // Wt[l][r][k][p] = W[l][r][c(p)][k]
    int idx = (bid - NGB - NCH) * 256 + t;
    int p  = idx & 127;
    int k  = (idx >> 7) & 127;
    int lr = idx >> 14;
    int l = lr / 9, r = lr - l * 9;
    int d = pos2col(p);
    float v;
    if (r < 8) v = W[((((size_t)l * 8 + r) * 128) + d) * 128 + k];
    else       v = Wl[(((size_t)l * 128) + d) * 128 + k];
    Wt[idx] = f2bf(v);
  } else {                               // biasP[l][p] = bias[l][c(p)]
    int l = t >> 7, p = t & 127;
    biasP[t] = bias[l * 128 + pos2col(p)];
  }
}

// ---- CSR pass B1: per-bucket chunk-prefix scan (196 blocks, 1 wave each) ----
__global__ void k_scan_buckets(const int* __restrict__ histT, int* __restrict__ curL,
                               int* __restrict__ btot) {
  const int b = blockIdx.x, tid = threadIdx.x;   // 64 threads
  int carry = 0;
  #pragma unroll
  for (int k = 0; k < 4; ++k) {
    int c = k * 64 + tid;
    int v = (c < NCH) ? histT[b * NCH + c] : 0;
    int incl = v;
    #pragma unroll
    for (int o = 1; o < 64; o <<= 1) {
      int nv = __shfl_up(incl, o);
      if (tid >= o) incl += nv;
    }
    if (c < NCH) curL[b * NCH + c] = carry + incl - v;
    carry += __shfl(incl, 63);
  }
  if (tid == 0) btot[b] = carry;
}

// ---- CSR pass B2: scan 196 bucket totals -> bbase ----
__global__ void k_scan_top(const int* __restrict__ btot, int* __restrict__ bbase,
                           int* __restrict__ rowptr) {
  const int t = threadIdx.x;
  int v = (t < NB) ? btot[t] : 0;
  int ex = block_scan_excl(v, t);
  if (t < NB) bbase[t] = ex;
  if (t == 0) { bbase[NB] = N_EDGES; rowptr[N_NODES] = N_EDGES; }
}

// ---- GEMM: A in regs, W staged per rel (round-16 proven), nt X stores ----
// X[rel][n][p] = sum A[n][.]*Wt[rel][.][.]
template <bool SCAT>
__global__ __launch_bounds__(256, 5) void k_gemm9(
    const unsigned short* __restrict__ A,   // [N][128] bf16 (permuted cols)
    const unsigned short* __restrict__ Bw,  // [9][128][128] bf16 (k x perm-d)
    unsigned short* __restrict__ X,         // [9][N][128] bf16 (permuted cols)
    const int* __restrict__ src, const int* __restrict__ dst,
    const int* __restrict__ et, const int* __restrict__ curL,
    const int* __restrict__ bbase, unsigned* __restrict__ tmp) {
  __shared__ unsigned char Ws[32768];   // 128 rows x 256B (swizzled)
  const int t = threadIdx.x;
  if (SCAT && blockIdx.x >= NMB) {      // chunk-local scatter role
    int* off2 = (int*)Ws;               // overlay LDS
    const int c = blockIdx.x - NMB;
    if (t < NB) off2[t] = curL[t * NCH + c] + bbase[t];
    __syncthreads();
    int base = c * CHUNK;
    #pragma unroll 4
    for (int i = t; i < CHUNK; i += 256) {
      int e = base + i;
      if (e < N_EDGES) {
        int d = dst[e];
        int pos = atomicAdd(&off2[d >> 8], 1);
        tmp[pos] = ((unsigned)(d & 255) << 19) | ((unsigned)et[e] << 16) | (unsigned)src[e];
      }
    }
    return;
  }
  const int mb = blockIdx.x;
  const int wid = t >> 6, lane = t & 63;
  const int lr = lane & 15, kg = (lane >> 4) * 8;
  const int rAg = mb * 64 + wid * 16 + lr;
  const bool rok = rAg < N_NODES;
  const unsigned short* Arow = A + (size_t)(rok ? rAg : 0) * 128;
  // hoist A fragments into registers ONCE (rel-invariant): 16 VGPRs
  s16x8 a[4];
  #pragma unroll
  for (int kk = 0; kk < 4; ++kk) {
    s16x8 v = (s16x8)(short)0;
    if (rok) v = *(const s16x8*)(Arow + kk * 32 + kg);
    a[kk] = v;
  }
  const unsigned char* Wb = (const unsigned char*)Bw;
  for (int rel = 0; rel < 9; ++rel) {
    // stage W_rel (32KB), swizzled
    const unsigned char* Bsrc = Wb + (size_t)rel * 32768;
    #pragma unroll
    for (int c = 0; c < 8; ++c) {
      int off = c * 4096 + t * 16;
      int row = off >> 8, ib = off & 255;
      *(u32x4*)(Ws + row * 256 + (ib ^ ((row & 7) << 4))) = *(const u32x4*)(Bsrc + off);
    }
    __syncthreads();
    f32x4 acc[8];
    #pragma unroll
    for (int n = 0; n < 8; ++n) acc[n] = (f32x4)(0.f);
    #pragma unroll
    for (int kk = 0; kk < 4; ++kk) {
      const int kb = (kk * 32 + kg) * 2;
      #pragma unroll
      for (int n = 0; n < 8; ++n) {
        int cc = n * 16 + lr;
        s16x8 b = *(const s16x8*)(Ws + cc * 256 + (kb ^ ((cc & 7) << 4)));
        acc[n] = __builtin_amdgcn_mfma_f32_16x16x32_bf16(a[kk], b, acc[n], 0, 0, 0);
      }
    }
    // epilogue: lane's 8 outputs pack into one 16B chunk at permuted positions
    // lr*8..lr*8+7 -> full-line coalesced stores; NONTEMPORAL (X >> L2, no
    // write-allocate benefit; consumed by a later kernel via L3/HBM)
    #pragma unroll
    for (int j = 0; j < 4; ++j) {
      int grow = mb * 64 + wid * 16 + (lane >> 4) * 4 + j;
      if (grow < N_NODES) {
        u32x4 pk;
        pk.x = (unsigned)f2bf(acc[0][j]) | ((unsigned)f2bf(acc[1][j]) << 16);
        pk.y = (unsigned)f2bf(acc[2][j]) | ((unsigned)f2bf(acc[3][j]) << 16);
        pk.z = (unsigned)f2bf(acc[4][j]) | ((unsigned)f2bf(acc[5][j]) << 16);
        pk.w = (unsigned)f2bf(acc[6][j]) | ((unsigned)f2bf(acc[7][j]) << 16);
        __builtin_nontemporal_store(
            pk, (u32x4*)((unsigned char*)X + ((size_t)rel * N_NODES + grow) * 256 + lr * 16));
      }
    }
    __syncthreads();   // all waves done with Ws before restage
  }
}

// ---- CSR finalize: per-node counting sort -> rowptr + u32 keys (et*N+src) ----
__global__ void k_bucket_finalize(const unsigned* __restrict__ tmp,
                                  const int* __restrict__ bbase,
                                  int* __restrict__ rowptr,
                                  unsigned* __restrict__ keys) {
  __shared__ int cnt[256];
  __shared__ int off[256];
  const int b = blockIdx.x;
  const int t = threadIdx.x;
  const int s = bbase[b], e = bbase[b + 1];
  cnt[t] = 0;
  __syncthreads();
  for (int i = s + t; i < e; i += 256)
    atomicAdd(&cnt[(tmp[i] >> 19) & 255u], 1);
  __syncthreads();
  int ex = block_scan_excl(cnt[t], t);
  int node = b * 256 + t;
  if (node < N_NODES) rowptr[node] = s + ex;
  off[t] = s + ex;
  __syncthreads();
  for (int i = s + t; i < e; i += 256) {
    unsigned r = tmp[i];
    int pos = atomicAdd(&off[(r >> 19) & 255u], 1);
    keys[pos] = ((r >> 16) & 7u) * N_NODES + (r & 0xffffu);
  }
}

// ---- per-node aggregation over CSR (permuted cols), 16-deep unroll ----
template <bool LAST>
__global__ void k_aggregate(const unsigned short* __restrict__ X,
                            const unsigned* __restrict__ keys,
                            const int* __restrict__ rowptr,
                            const float* __restrict__ biasP,
                            void* __restrict__ out) {
  __shared__ float ob[4][128];
  const int t = threadIdx.x;
  const int w = t >> 6;
  const int v = blockIdx.x * 4 + w;
  const int lane = t & 63;
  const int start = rowptr[v], end = rowptr[v + 1];
  const unsigned char* Xb = (const unsigned char*)X;
  float a0 = 0.f, a1 = 0.f;
  int e = start;
  const int n16 = start + ((end - start) & ~15);
  for (; e < n16; e += 16) {
    unsigned kk[16], pp[16];
    #pragma unroll
    for (int q = 0; q < 16; ++q) kk[q] = keys[e + q];
    #pragma unroll
    for (int q = 0; q < 16; ++q)
      pp[q] = *(const unsigned*)(Xb + ((size_t)kk[q] << 8) + lane * 4);
    #pragma unroll
    for (int q = 0; q < 16; ++q) {
      a0 += __uint_as_float(pp[q] << 16);
      a1 += __uint_as_float(pp[q] & 0xffff0000u);
    }
  }
  const int n4 = start + ((end - start) & ~3);
  for (; e < n4; e += 4) {
    unsigned kk[4], pp[4];
    #pragma unroll
    for (int q = 0; q < 4; ++q) kk[q] = keys[e + q];
    #pragma unroll
    for (int q = 0; q < 4; ++q)
      pp[q] = *(const unsigned*)(Xb + ((size_t)kk[q] << 8) + lane * 4);
    #pragma unroll
    for (int q = 0; q < 4; ++q) {
      a0 += __uint_as_float(pp[q] << 16);
      a1 += __uint_as_float(pp[q] & 0xffff0000u);
    }
  }
  for (; e < end; ++e) {
    unsigned k0 = keys[e];
    unsigned p0 = *(const unsigned*)(Xb + ((size_t)k0 << 8) + lane * 4);
    a0 += __uint_as_float(p0 << 16); a1 += __uint_as_float(p0 & 0xffff0000u);
  }
  { // self-loop pseudo-relation row
    unsigned p = *(const unsigned*)(Xb + (((size_t)8 * N_NODES + v) << 8) + lane * 4);
    a0 += __uint_as_float(p << 16); a1 += __uint_as_float(p & 0xffff0000u);
  }
  const float2 bb = *(const float2*)(biasP + lane * 2);
  a0 += bb.x; a1 += bb.y;
  if (LAST) {
    // un-permute: position 2L -> natural col c0, 2L+1 -> c0+16
    int c0 = ((2 * lane) & 7) * 16 + (lane >> 2);
    ob[w][c0] = a0;
    ob[w][c0 + 16] = a1;
    __syncthreads();
    f32x2 o = *(const f32x2*)&ob[w][lane * 2];
    __builtin_nontemporal_store(o, (f32x2*)((float*)out + (size_t)v * 128 + lane * 2));
  } else {
    unsigned po = ((unsigned)f2bf(a1) << 16) | (unsigned)f2bf(a0);
    *(unsigned*)((unsigned short*)out + (size_t)v * 128 + lane * 2) = po;
  }
}

extern "C" void kernel_launch(void* const* d_in, const int* in_sizes, int n_in,
                              void* d_out, int out_size, void* d_ws, size_t ws_size,
                              hipStream_t stream) {
  const int*   nid  = (const int*)d_in[0];
  const int*   src  = (const int*)d_in[1];
  const int*   dst  = (const int*)d_in[2];
  const int*   et   = (const int*)d_in[3];
  const float* emb  = (const float*)d_in[4];
  const float* W    = (const float*)d_in[5];
  const float* Wl   = (const float*)d_in[6];
  const float* bias = (const float*)d_in[7];

  unsigned char* ws = (unsigned char*)d_ws;
  size_t off = 0;
  auto alloc = [&](size_t bytes) {
    void* p = ws + off;
    off = (off + bytes + 255) & ~(size_t)255;
    return p;
  };
  unsigned short* X    = (unsigned short*)alloc((size_t)9 * N_NODES * HID * 2);  // 115.2 MB
  unsigned short* h0   = (unsigned short*)alloc((size_t)N_NODES * HID * 2);      // 12.8 MB
  unsigned short* h1   = (unsigned short*)alloc((size_t)N_NODES * HID * 2);      // 12.8 MB
  unsigned short* Wt   = (unsigned short*)alloc((size_t)2 * 9 * 128 * 128 * 2);  // 0.6 MB
  unsigned*       keys = (unsigned*)alloc((size_t)N_EDGES * 4);                  // 6.4 MB
  int*            rowp = (int*)alloc((size_t)(N_NODES + 1) * 4);
  int*            histT= (int*)alloc((size_t)TOT * 4);                           // 150 KB
  int*            curL = (int*)alloc((size_t)TOT * 4);                           // 150 KB
  int*            btot = (int*)alloc((size_t)NB * 4);
  int*            bbas = (int*)alloc((size_t)(NB + 1) * 4);
  float*          biasP= (float*)alloc((size_t)2 * 128 * 4);
  // scatter tmp aliases h1 (dead until aggregate-L0)
  unsigned*       tmp  = (unsigned*)h1;

  k_pre<<<NGB + NCH + NCW + 1, 256, 0, stream>>>(nid, emb, h0, dst, histT, W, Wl, Wt,
                                                 bias, biasP);
  k_scan_buckets<<<NB, 64, 0, stream>>>(histT, curL, btot);
  k_scan_top<<<1, 256, 0, stream>>>(btot, bbas, rowp);
  // gemm layer 0 (782 blocks) + chunk_scatter (196 blocks) fused
  k_gemm9<true><<<NMB + NCH, 256, 0, stream>>>(h0, Wt, X, src, dst, et, curL, bbas, tmp);
  k_bucket_finalize<<<NB, 256, 0, stream>>>(tmp, bbas, rowp, keys);

  const int agrid = N_NODES / 4;                 // 12500, one wave per node
  k_aggregate<false><<<agrid, 256, 0, stream>>>(X, keys, rowp, biasP, (void*)h1);
  k_gemm9<false><<<NMB, 256, 0, stream>>>(h1, Wt + (size_t)9 * 128 * 128, X,
                                          src, dst, et, curL, bbas, tmp);
  k_aggregate<true><<<agrid, 256, 0, stream>>>(X, keys, rowp, biasP + HID, (void*)d_out);
}

// Round 21
// 241.797 us; speedup vs baseline: 1.0445x; 1.0345x over previous
//
#include <hip/hip_runtime.h>
#include <stdint.h>

#define N_NODES 50000
#define N_EDGES 1600000
#define HID 128
#define NB 196      // dst buckets of 256 nodes
#define CHUNK 8192
#define NCH 196     // ceil(1600000 / 8192)
#define TOT (NB * NCH)
#define NGB 6250    // gather_h0 blocks (N*32/256)
#define NCW 1152    // convert_w blocks
#define NMB 782     // gemm 64-row tiles

typedef float f32x4 __attribute__((ext_vector_type(4)));
typedef float f32x2 __attribute__((ext_vector_type(2)));
typedef short s16x8 __attribute__((ext_vector_type(8)));
typedef unsigned u32x4 __attribute__((ext_vector_type(4)));

// permuted X/h column layout: natural col c lives at position p
//   p(c) = (c&15)*8 + (c>>4)      c(p) = (p&7)*16 + (p>>3)
__device__ __forceinline__ int pos2col(int p) { return (p & 7) * 16 + (p >> 3); }

__device__ __forceinline__ unsigned short f2bf(float f) {
  unsigned u = __float_as_uint(f);
  u += 0x7fffu + ((u >> 16) & 1u);   // RNE
  return (unsigned short)(u >> 16);
}

__device__ __forceinline__ int block_scan_excl(int v, int t) {
  const int lane = t & 63, wid = t >> 6;
  int incl = v;
  #pragma unroll
  for (int o = 1; o < 64; o <<= 1) {
    int nv = __shfl_up(incl, o);
    if (lane >= o) incl += nv;
  }
  __shared__ int wsum[4];
  if (lane == 63) wsum[wid] = incl;
  __syncthreads();
  int wbase = 0;
  #pragma unroll
  for (int w = 0; w < 3; ++w) if (w < wid) wbase += wsum[w];
  return wbase + incl - v;
}

// ---- pre-kernel: gather_h0(perm) | chunk_hist | convert_w(perm-d) | biasP ----
__global__ void k_pre(const int* __restrict__ nid, const float* __restrict__ emb,
                      unsigned short* __restrict__ h0,
                      const int* __restrict__ dst, int* __restrict__ histT,
                      const float* __restrict__ W, const float* __restrict__ Wl,
                      unsigned short* __restrict__ Wt,
                      const float* __restrict__ bias, float* __restrict__ biasP) {
  const int bid = blockIdx.x, t = threadIdx.x;
  if (bid < NGB) {                       // h0[i][p] = bf16(emb[nid[i]][c(p)])
    int g = bid * 256 + t;
    int i = g >> 5, s = g & 31;
    const float* erow = emb + (size_t)nid[i] * HID;
    ushort4 o;
    o.x = f2bf(erow[pos2col(4 * s + 0)]);
    o.y = f2bf(erow[pos2col(4 * s + 1)]);
    o.z = f2bf(erow[pos2col(4 * s + 2)]);
    o.w = f2bf(erow[pos2col(4 * s + 3)]);
    *(ushort4*)(h0 + (size_t)i * HID + 4 * s) = o;
  } else if (bid < NGB + NCH) {          // per-chunk bucket histogram
    __shared__ int h[NB];
    const int c = bid - NGB;
    if (t < NB) h[t] = 0;
    __syncthreads();
    int base = c * CHUNK;
    #pragma unroll 4
    for (int i = t; i < CHUNK; i += 256) {
      int e = base + i;
      if (e < N_EDGES) atomicAdd(&h[dst[e] >> 8], 1);
    }
    __syncthreads();
    if (t < NB) histT[t * NCH + c] = h[t];
  } else if (bid < NGB + NCH + NCW) {    // Wt[l][r][k][p] = W[l][r][c(p)][k]
    int idx = (bid - NGB - NCH) * 256 + t;
    int p  = idx & 127;
    int k  = (idx >> 7) & 127;
    int lr = idx >> 14;
    int l = lr / 9, r = lr - l * 9;
    int d = pos2col(p);
    float v;
    if (r < 8) v = W[((((size_t)l * 8 + r) * 128) + d) * 128 + k];
    else       v = Wl[(((size_t)l * 128) + d) * 128 + k];
    Wt[idx] = f2bf(v);
  } else {                               // biasP[l][p] = bias[l][c(p)]
    int l = t >> 7, p = t & 127;
    biasP[t] = bias[l * 128 + pos2col(p)];
  }
}

// ---- CSR pass B1: per-bucket chunk-prefix scan (196 blocks, 1 wave each) ----
__global__ void k_scan_buckets(const int* __restrict__ histT, int* __restrict__ curL,
                               int* __restrict__ btot) {
  const int b = blockIdx.x, tid = threadIdx.x;   // 64 threads
  int carry = 0;
  #pragma unroll
  for (int k = 0; k < 4; ++k) {
    int c = k * 64 + tid;
    int v = (c < NCH) ? histT[b * NCH + c] : 0;
    int incl = v;
    #pragma unroll
    for (int o = 1; o < 64; o <<= 1) {
      int nv = __shfl_up(incl, o);
      if (tid >= o) incl += nv;
    }
    if (c < NCH) curL[b * NCH + c] = carry + incl - v;
    carry += __shfl(incl, 63);
  }
  if (tid == 0) btot[b] = carry;
}

// ---- CSR pass B2: scan 196 bucket totals -> bbase ----
__global__ void k_scan_top(const int* __restrict__ btot, int* __restrict__ bbase,
                           int* __restrict__ rowptr) {
  const int t = threadIdx.x;
  int v = (t < NB) ? btot[t] : 0;
  int ex = block_scan_excl(v, t);
  if (t < NB) bbase[t] = ex;
  if (t == 0) { bbase[NB] = N_EDGES; rowptr[N_NODES] = N_EDGES; }
}

// ---- GEMM: A in regs (rel-invariant), W staged per rel, coalesced stores ----
// X[rel][n][p] = sum A[n][.]*Wt[rel][.][.]   [round-16 proven best]
template <bool SCAT>
__global__ __launch_bounds__(256, 5) void k_gemm9(
    const unsigned short* __restrict__ A,   // [N][128] bf16 (permuted cols)
    const unsigned short* __restrict__ Bw,  // [9][128][128] bf16 (k x perm-d)
    unsigned short* __restrict__ X,         // [9][N][128] bf16 (permuted cols)
    const int* __restrict__ src, const int* __restrict__ dst,
    const int* __restrict__ et, const int* __restrict__ curL,
    const int* __restrict__ bbase, unsigned* __restrict__ tmp) {
  __shared__ unsigned char Ws[32768];   // 128 rows x 256B (swizzled)
  const int t = threadIdx.x;
  if (SCAT && blockIdx.x >= NMB) {      // chunk-local scatter role
    int* off2 = (int*)Ws;               // overlay LDS
    const int c = blockIdx.x - NMB;
    if (t < NB) off2[t] = curL[t * NCH + c] + bbase[t];
    __syncthreads();
    int base = c * CHUNK;
    #pragma unroll 4
    for (int i = t; i < CHUNK; i += 256) {
      int e = base + i;
      if (e < N_EDGES) {
        int d = dst[e];
        int pos = atomicAdd(&off2[d >> 8], 1);
        tmp[pos] = ((unsigned)(d & 255) << 19) | ((unsigned)et[e] << 16) | (unsigned)src[e];
      }
    }
    return;
  }
  const int mb = blockIdx.x;
  const int wid = t >> 6, lane = t & 63;
  const int lr = lane & 15, kg = (lane >> 4) * 8;
  const int rAg = mb * 64 + wid * 16 + lr;
  const bool rok = rAg < N_NODES;
  const unsigned short* Arow = A + (size_t)(rok ? rAg : 0) * 128;
  // hoist A fragments into registers ONCE (rel-invariant): 16 VGPRs
  s16x8 a[4];
  #pragma unroll
  for (int kk = 0; kk < 4; ++kk) {
    s16x8 v = (s16x8)(short)0;
    if (rok) v = *(const s16x8*)(Arow + kk * 32 + kg);
    a[kk] = v;
  }
  const unsigned char* Wb = (const unsigned char*)Bw;
  for (int rel = 0; rel < 9; ++rel) {
    // stage W_rel (32KB), swizzled
    const unsigned char* Bsrc = Wb + (size_t)rel * 32768;
    #pragma unroll
    for (int c = 0; c < 8; ++c) {
      int off = c * 4096 + t * 16;
      int row = off >> 8, ib = off & 255;
      *(u32x4*)(Ws + row * 256 + (ib ^ ((row & 7) << 4))) = *(const u32x4*)(Bsrc + off);
    }
    __syncthreads();
    f32x4 acc[8];
    #pragma unroll
    for (int n = 0; n < 8; ++n) acc[n] = (f32x4)(0.f);
    #pragma unroll
    for (int kk = 0; kk < 4; ++kk) {
      const int kb = (kk * 32 + kg) * 2;
      #pragma unroll
      for (int n = 0; n < 8; ++n) {
        int cc = n * 16 + lr;
        s16x8 b = *(const s16x8*)(Ws + cc * 256 + (kb ^ ((cc & 7) << 4)));
        acc[n] = __builtin_amdgcn_mfma_f32_16x16x32_bf16(a[kk], b, acc[n], 0, 0, 0);
      }
    }
    // epilogue: lane's 8 outputs pack into one 16B chunk at permuted positions
    // lr*8..lr*8+7 -> full-line coalesced stores (4 x 256B rows per wave-instr)
    #pragma unroll
    for (int j = 0; j < 4; ++j) {
      int grow = mb * 64 + wid * 16 + (lane >> 4) * 4 + j;
      if (grow < N_NODES) {
        u32x4 pk;
        pk.x = (unsigned)f2bf(acc[0][j]) | ((unsigned)f2bf(acc[1][j]) << 16);
        pk.y = (unsigned)f2bf(acc[2][j]) | ((unsigned)f2bf(acc[3][j]) << 16);
        pk.z = (unsigned)f2bf(acc[4][j]) | ((unsigned)f2bf(acc[5][j]) << 16);
        pk.w = (unsigned)f2bf(acc[6][j]) | ((unsigned)f2bf(acc[7][j]) << 16);
        *(u32x4*)((unsigned char*)X + ((size_t)rel * N_NODES + grow) * 256 + lr * 16) = pk;
      }
    }
    __syncthreads();   // all waves done with Ws before restage
  }
}

// ---- CSR finalize: per-node counting sort -> rowptr + u32 keys (et*N+src) ----
__global__ void k_bucket_finalize(const unsigned* __restrict__ tmp,
                                  const int* __restrict__ bbase,
                                  int* __restrict__ rowptr,
                                  unsigned* __restrict__ keys) {
  __shared__ int cnt[256];
  __shared__ int off[256];
  const int b = blockIdx.x;
  const int t = threadIdx.x;
  const int s = bbase[b], e = bbase[b + 1];
  cnt[t] = 0;
  __syncthreads();
  for (int i = s + t; i < e; i += 256)
    atomicAdd(&cnt[(tmp[i] >> 19) & 255u], 1);
  __syncthreads();
  int ex = block_scan_excl(cnt[t], t);
  int node = b * 256 + t;
  if (node < N_NODES) rowptr[node] = s + ex;
  off[t] = s + ex;
  __syncthreads();
  for (int i = s + t; i < e; i += 256) {
    unsigned r = tmp[i];
    int pos = atomicAdd(&off[(r >> 19) & 255u], 1);
    keys[pos] = ((r >> 16) & 7u) * N_NODES + (r & 0xffffu);
  }
}

// ---- per-node aggregation over CSR (permuted cols), 16-deep unroll ----
template <bool LAST>
__global__ void k_aggregate(const unsigned short* __restrict__ X,
                            const unsigned* __restrict__ keys,
                            const int* __restrict__ rowptr,
                            const float* __restrict__ biasP,
                            void* __restrict__ out) {
  __shared__ float ob[4][128];
  const int t = threadIdx.x;
  const int w = t >> 6;
  const int v = blockIdx.x * 4 + w;
  const int lane = t & 63;
  const int start = rowptr[v], end = rowptr[v + 1];
  const unsigned char* Xb = (const unsigned char*)X;
  float a0 = 0.f, a1 = 0.f;
  int e = start;
  const int n16 = start + ((end - start) & ~15);
  for (; e < n16; e += 16) {
    unsigned kk[16], pp[16];
    #pragma unroll
    for (int q = 0; q < 16; ++q) kk[q] = keys[e + q];
    #pragma unroll
    for (int q = 0; q < 16; ++q)
      pp[q] = *(const unsigned*)(Xb + ((size_t)kk[q] << 8) + lane * 4);
    #pragma unroll
    for (int q = 0; q < 16; ++q) {
      a0 += __uint_as_float(pp[q] << 16);
      a1 += __uint_as_float(pp[q] & 0xffff0000u);
    }
  }
  const int n4 = start + ((end - start) & ~3);
  for (; e < n4; e += 4) {
    unsigned kk[4], pp[4];
    #pragma unroll
    for (int q = 0; q < 4; ++q) kk[q] = keys[e + q];
    #pragma unroll
    for (int q = 0; q < 4; ++q)
      pp[q] = *(const unsigned*)(Xb + ((size_t)kk[q] << 8) + lane * 4);
    #pragma unroll
    for (int q = 0; q < 4; ++q) {
      a0 += __uint_as_float(pp[q] << 16);
      a1 += __uint_as_float(pp[q] & 0xffff0000u);
    }
  }
  for (; e < end; ++e) {
    unsigned k0 = keys[e];
    unsigned p0 = *(const unsigned*)(Xb + ((size_t)k0 << 8) + lane * 4);
    a0 += __uint_as_float(p0 << 16); a1 += __uint_as_float(p0 & 0xffff0000u);
  }
  { // self-loop pseudo-relation row
    unsigned p = *(const unsigned*)(Xb + (((size_t)8 * N_NODES + v) << 8) + lane * 4);
    a0 += __uint_as_float(p << 16); a1 += __uint_as_float(p & 0xffff0000u);
  }
  const float2 bb = *(const float2*)(biasP + lane * 2);
  a0 += bb.x; a1 += bb.y;
  if (LAST) {
    // un-permute: position 2L -> natural col c0, 2L+1 -> c0+16
    int c0 = ((2 * lane) & 7) * 16 + (lane >> 2);
    ob[w][c0] = a0;
    ob[w][c0 + 16] = a1;
    __syncthreads();
    f32x2 o = *(const f32x2*)&ob[w][lane * 2];
    __builtin_nontemporal_store(o, (f32x2*)((float*)out + (size_t)v * 128 + lane * 2));
  } else {
    unsigned po = ((unsigned)f2bf(a1) << 16) | (unsigned)f2bf(a0);
    *(unsigned*)((unsigned short*)out + (size_t)v * 128 + lane * 2) = po;
  }
}

extern "C" void kernel_launch(void* const* d_in, const int* in_sizes, int n_in,
                              void* d_out, int out_size, void* d_ws, size_t ws_size,
                              hipStream_t stream) {
  const int*   nid  = (const int*)d_in[0];
  const int*   src  = (const int*)d_in[1];
  const int*   dst  = (const int*)d_in[2];
  const int*   et   = (const int*)d_in[3];
  const float* emb  = (const float*)d_in[4];
  const float* W    = (const float*)d_in[5];
  const float* Wl   = (const float*)d_in[6];
  const float* bias = (const float*)d_in[7];

  unsigned char* ws = (unsigned char*)d_ws;
  size_t off = 0;
  auto alloc = [&](size_t bytes) {
    void* p = ws + off;
    off = (off + bytes + 255) & ~(size_t)255;
    return p;
  };
  unsigned short* X    = (unsigned short*)alloc((size_t)9 * N_NODES * HID * 2);  // 115.2 MB
  unsigned short* h0   = (unsigned short*)alloc((size_t)N_NODES * HID * 2);      // 12.8 MB
  unsigned short* h1   = (unsigned short*)alloc((size_t)N_NODES * HID * 2);      // 12.8 MB
  unsigned short* Wt   = (unsigned short*)alloc((size_t)2 * 9 * 128 * 128 * 2);  // 0.6 MB
  unsigned*       keys = (unsigned*)alloc((size_t)N_EDGES * 4);                  // 6.4 MB
  int*            rowp = (int*)alloc((size_t)(N_NODES + 1) * 4);
  int*            histT= (int*)alloc((size_t)TOT * 4);                           // 150 KB
  int*            curL = (int*)alloc((size_t)TOT * 4);                           // 150 KB
  int*            btot = (int*)alloc((size_t)NB * 4);
  int*            bbas = (int*)alloc((size_t)(NB + 1) * 4);
  float*          biasP= (float*)alloc((size_t)2 * 128 * 4);
  // scatter tmp aliases h1 (dead until aggregate-L0)
  unsigned*       tmp  = (unsigned*)h1;

  k_pre<<<NGB + NCH + NCW + 1, 256, 0, stream>>>(nid, emb, h0, dst, histT, W, Wl, Wt,
                                                 bias, biasP);
  k_scan_buckets<<<NB, 64, 0, stream>>>(histT, curL, btot);
  k_scan_top<<<1, 256, 0, stream>>>(btot, bbas, rowp);
  // gemm layer 0 (782 blocks) + chunk_scatter (196 blocks) fused
  k_gemm9<true><<<NMB + NCH, 256, 0, stream>>>(h0, Wt, X, src, dst, et, curL, bbas, tmp);
  k_bucket_finalize<<<NB, 256, 0, stream>>>(tmp, bbas, rowp, keys);

  const int agrid = N_NODES / 4;                 // 12500, one wave per node
  k_aggregate<false><<<agrid, 256, 0, stream>>>(X, keys, rowp, biasP, (void*)h1);
  k_gemm9<false><<<NMB, 256, 0, stream>>>(h1, Wt + (size_t)9 * 128 * 128, X,
                                          src, dst, et, curL, bbas, tmp);
  k_aggregate<true><<<agrid, 256, 0, stream>>>(X, keys, rowp, biasP + HID, (void*)d_out);
}